// Round 1
// baseline (104.337 us; speedup 1.0000x reference)
//
#include <hip/hip_runtime.h>
#include <hip/hip_bf16.h>

// p_new = p + a * tanh(q);  out = [p_new, q]  (rows of 2*DIM fp32)
// DIM = 2048 -> 512 float4 per half-row, 1024 float4 per row.

#define DIM 2048
#define HALF4 (DIM / 4)          // 512 float4 per half-row
#define ROW4 (2 * HALF4)         // 1024 float4 per full row

__device__ __forceinline__ float tanh_fast(float x) {
    // tanh(x) = 1 - 2/(exp(2x)+1); exp overflow->inf gives 1, underflow->0 gives -1.
    float e = __expf(2.0f * x);
    return 1.0f - 2.0f / (e + 1.0f);
}

__global__ void __launch_bounds__(256)
act_kernel(const float4* __restrict__ pq, const float4* __restrict__ a,
           float4* __restrict__ out, long total_half4) {
    long stride = (long)gridDim.x * blockDim.x;
    for (long i = (long)blockIdx.x * blockDim.x + threadIdx.x; i < total_half4; i += stride) {
        int col = (int)(i & (HALF4 - 1));       // float4 index within half-row
        long row = i >> 9;                      // i / HALF4
        long base = row * ROW4;

        float4 p = pq[base + col];
        float4 q = pq[base + HALF4 + col];
        float4 av = a[col];

        float4 r;
        r.x = p.x + av.x * tanh_fast(q.x);
        r.y = p.y + av.y * tanh_fast(q.y);
        r.z = p.z + av.z * tanh_fast(q.z);
        r.w = p.w + av.w * tanh_fast(q.w);

        out[base + col] = r;
        out[base + HALF4 + col] = q;
    }
}

extern "C" void kernel_launch(void* const* d_in, const int* in_sizes, int n_in,
                              void* d_out, int out_size, void* d_ws, size_t ws_size,
                              hipStream_t stream) {
    const float4* pq = (const float4*)d_in[0];
    const float4* a  = (const float4*)d_in[1];
    float4* out = (float4*)d_out;

    long rows = (long)in_sizes[0] / (2 * DIM);     // 16384
    long total_half4 = rows * HALF4;               // 8,388,608 float4 work items

    dim3 block(256);
    dim3 grid(2048);
    act_kernel<<<grid, block, 0, stream>>>(pq, a, out, total_half4);
}

// Round 3
// 103.866 us; speedup vs baseline: 1.0045x; 1.0045x over previous
//
#include <hip/hip_runtime.h>
#include <hip/hip_bf16.h>

// p_new = p + a * tanh(q);  out = [p_new, q]  (rows of 2*DIM fp32)
// DIM = 2048 -> 512 float4 per half-row, 1024 float4 per row.
// Streaming-once data: non-temporal loads/stores to avoid L2/LLC pollution.

#define DIM 2048
#define HALF4 (DIM / 4)          // 512 float4 per half-row
#define ROW4 (2 * HALF4)         // 1024 float4 per full row

// Native clang vector type: nontemporal builtins reject HIP_vector_type.
typedef float f4 __attribute__((ext_vector_type(4)));

__device__ __forceinline__ float tanh_fast(float x) {
    // tanh(x) = 1 - 2/(exp(2x)+1); exp overflow->inf gives 1, underflow->0 gives -1.
    float e = __expf(2.0f * x);
    return 1.0f - 2.0f / (e + 1.0f);
}

__device__ __forceinline__ f4 act4(f4 p, f4 q, f4 av) {
    f4 r;
    r.x = p.x + av.x * tanh_fast(q.x);
    r.y = p.y + av.y * tanh_fast(q.y);
    r.z = p.z + av.z * tanh_fast(q.z);
    r.w = p.w + av.w * tanh_fast(q.w);
    return r;
}

__global__ void __launch_bounds__(256)
act_kernel(const f4* __restrict__ pq, const f4* __restrict__ a,
           f4* __restrict__ out, long total_half4) {
    const long stride = (long)gridDim.x * blockDim.x;
    long i = (long)blockIdx.x * blockDim.x + threadIdx.x;

    // Main 2x-unrolled grid-stride loop: 4 independent loads in flight.
    for (; i + stride < total_half4; i += 2 * stride) {
        long i2 = i + stride;
        int  col0 = (int)(i  & (HALF4 - 1));
        int  col1 = (int)(i2 & (HALF4 - 1));
        long base0 = (i  >> 9) * ROW4;
        long base1 = (i2 >> 9) * ROW4;

        f4 p0 = __builtin_nontemporal_load(&pq[base0 + col0]);
        f4 q0 = __builtin_nontemporal_load(&pq[base0 + HALF4 + col0]);
        f4 p1 = __builtin_nontemporal_load(&pq[base1 + col1]);
        f4 q1 = __builtin_nontemporal_load(&pq[base1 + HALF4 + col1]);
        f4 a0 = a[col0];
        f4 a1 = a[col1];

        f4 r0 = act4(p0, q0, a0);
        f4 r1 = act4(p1, q1, a1);

        __builtin_nontemporal_store(r0, &out[base0 + col0]);
        __builtin_nontemporal_store(q0, &out[base0 + HALF4 + col0]);
        __builtin_nontemporal_store(r1, &out[base1 + col1]);
        __builtin_nontemporal_store(q1, &out[base1 + HALF4 + col1]);
    }
    // Tail
    for (; i < total_half4; i += stride) {
        int  col = (int)(i & (HALF4 - 1));
        long base = (i >> 9) * ROW4;
        f4 p = __builtin_nontemporal_load(&pq[base + col]);
        f4 q = __builtin_nontemporal_load(&pq[base + HALF4 + col]);
        f4 r = act4(p, q, a[col]);
        __builtin_nontemporal_store(r, &out[base + col]);
        __builtin_nontemporal_store(q, &out[base + HALF4 + col]);
    }
}

extern "C" void kernel_launch(void* const* d_in, const int* in_sizes, int n_in,
                              void* d_out, int out_size, void* d_ws, size_t ws_size,
                              hipStream_t stream) {
    const f4* pq = (const f4*)d_in[0];
    const f4* a  = (const f4*)d_in[1];
    f4* out = (f4*)d_out;

    long rows = (long)in_sizes[0] / (2 * DIM);     // 16384
    long total_half4 = rows * HALF4;               // 8,388,608 float4 work items

    dim3 block(256);
    dim3 grid(2048);
    act_kernel<<<grid, block, 0, stream>>>(pq, a, out, total_half4);
}

// Round 4
// 88.591 us; speedup vs baseline: 1.1777x; 1.1724x over previous
//
#include <hip/hip_runtime.h>
#include <hip/hip_bf16.h>

// p_new = p + a * tanh(q);  out = [p_new, q]  (rows of 2*DIM fp32)
// DIM = 2048 -> 512 float4 per half-row, 1024 float4 per row.
// One-pass launch: one float4-pair per thread, no grid-stride loop.
// 16384 rows * 512 half4 = 8,388,608 threads = 32768 blocks x 256.

#define DIM 2048
#define HALF4 (DIM / 4)          // 512 float4 per half-row
#define ROW4 (2 * HALF4)         // 1024 float4 per full row

// Native clang vector type: nontemporal builtins reject HIP_vector_type.
typedef float f4 __attribute__((ext_vector_type(4)));

__device__ __forceinline__ float tanh_fast(float x) {
    // tanh(x) = 1 - 2/(exp(2x)+1); exp overflow->inf gives 1, underflow->0 gives -1.
    float e = __expf(2.0f * x);
    return 1.0f - 2.0f / (e + 1.0f);
}

__global__ void __launch_bounds__(256)
act_kernel(const f4* __restrict__ pq, const f4* __restrict__ a,
           f4* __restrict__ out) {
    long i = (long)blockIdx.x * blockDim.x + threadIdx.x;
    int  col = (int)(i & (HALF4 - 1));       // float4 index within half-row
    long base = (i >> 9) * ROW4;             // row * ROW4

    f4 p = __builtin_nontemporal_load(&pq[base + col]);
    f4 q = __builtin_nontemporal_load(&pq[base + HALF4 + col]);

    // q passthrough is independent of the tanh chain — issue it first.
    __builtin_nontemporal_store(q, &out[base + HALF4 + col]);

    f4 av = a[col];
    f4 r;
    r.x = p.x + av.x * tanh_fast(q.x);
    r.y = p.y + av.y * tanh_fast(q.y);
    r.z = p.z + av.z * tanh_fast(q.z);
    r.w = p.w + av.w * tanh_fast(q.w);

    __builtin_nontemporal_store(r, &out[base + col]);
}

extern "C" void kernel_launch(void* const* d_in, const int* in_sizes, int n_in,
                              void* d_out, int out_size, void* d_ws, size_t ws_size,
                              hipStream_t stream) {
    const f4* pq = (const f4*)d_in[0];
    const f4* a  = (const f4*)d_in[1];
    f4* out = (f4*)d_out;

    long rows = (long)in_sizes[0] / (2 * DIM);     // 16384
    long total_half4 = rows * HALF4;               // 8,388,608

    dim3 block(256);
    dim3 grid((unsigned)((total_half4 + 255) / 256));   // 32768 one-pass blocks
    act_kernel<<<grid, block, 0, stream>>>(pq, a, out);
}